// Round 10
// baseline (221.757 us; speedup 1.0000x reference)
//
#include <hip/hip_runtime.h>
#include <cmath>

// Problem constants (B=4, S=4096, D=4096, E=64, K=8)
#define NTOK 16384
#define DDIM 4096
#define NEXP 64
#define TOPK 8
#define TPB   16                // tokens per block (one 16-row fragment)
#define KSPLIT 4                // waves per block = K-split ways
#define KSL   1024              // K per wave slice
#define NSTEP 32                // steps of 32 k per wave
#define EPS_GAP 2.5e-4f         // ambiguity margin; trunc-split err sigma ~1e-6

typedef __attribute__((ext_vector_type(8))) short short8;   // 8 bf16
typedef __attribute__((ext_vector_type(4))) float f32x4;

__device__ __forceinline__ void gload16(const void* g, void* l) {
    __builtin_amdgcn_global_load_lds(
        (const __attribute__((address_space(1))) unsigned int*)g,
        (__attribute__((address_space(3))) unsigned int*)l, 16, 0, 0);
}

// trunc split: hi = top 16 bits (residual exact), lo = trunc16(f - hi).
#define CVT1(f, hOut, lOut, j) do {                                          \
    unsigned _u = __builtin_bit_cast(unsigned, (float)(f));                  \
    float _hf = __builtin_bit_cast(float, _u & 0xFFFF0000u);                 \
    hOut[j] = (short)(_u >> 16);                                             \
    lOut[j] = (short)(__builtin_bit_cast(unsigned, (float)((f) - _hf)) >> 16);\
} while (0)
#define CONV8(vA, vB, hOut, lOut) do {                       \
    CVT1(vA.x, hOut, lOut, 0); CVT1(vA.y, hOut, lOut, 1);    \
    CVT1(vA.z, hOut, lOut, 2); CVT1(vA.w, hOut, lOut, 3);    \
    CVT1(vB.x, hOut, lOut, 4); CVT1(vB.y, hOut, lOut, 5);    \
    CVT1(vB.z, hOut, lOut, 6); CVT1(vB.w, hOut, lOut, 7);    \
} while (0)

// ---------------------------------------------------------------------------
// Kernel 0: pack W into fragment-LANE-ordered blob:
// blob[c32 0..127][n 0..3][h 0..1][granule 0..63 * 16B], granule index =
// kgrp*16 + e_local == the consuming lane id. A wave's B load is then ONE
// wave-linear 1KB dwordx4 per (n,h). Also zeroes the flag counter.
// ---------------------------------------------------------------------------
__global__ __launch_bounds__(256) void prep_w(const float* __restrict__ W,
                                              unsigned char* __restrict__ blob,
                                              int* __restrict__ flag_cnt)
{
    __shared__ float tile[32][65];
    const int c = blockIdx.x;                 // k-window [c*32, c*32+32)
    const int t = threadIdx.x;
    if (c == 0 && t == 0) *flag_cnt = 0;
    {
        const int r = t >> 3, q = t & 7;      // row, 8-float slice
        float4 v0 = *reinterpret_cast<const float4*>(
            &W[(size_t)(c * 32 + r) * NEXP + q * 8]);
        float4 v1 = *reinterpret_cast<const float4*>(
            &W[(size_t)(c * 32 + r) * NEXP + q * 8 + 4]);
        tile[r][q * 8 + 0] = v0.x; tile[r][q * 8 + 1] = v0.y;
        tile[r][q * 8 + 2] = v0.z; tile[r][q * 8 + 3] = v0.w;
        tile[r][q * 8 + 4] = v1.x; tile[r][q * 8 + 5] = v1.y;
        tile[r][q * 8 + 6] = v1.z; tile[r][q * 8 + 7] = v1.w;
    }
    __syncthreads();
    {
        const int el   = t & 15;              // e_local
        const int kgrp = (t >> 4) & 3;
        const int n    = t >> 6;
        short8 hv, lv;
#pragma unroll
        for (int j = 0; j < 8; ++j) {
            float f = tile[kgrp * 8 + j][n * 16 + el];
            CVT1(f, hv, lv, j);
        }
        unsigned char* base = blob + (size_t)c * 8192 + n * 2048 +
                              (kgrp * 16 + el) * 16;
        *reinterpret_cast<short8*>(base)        = hv;   // hi
        *reinterpret_cast<short8*>(base + 1024) = lv;   // lo
    }
}

// ---------------------------------------------------------------------------
// Kernel 1: wave-autonomous MFMA GEMM. 1024 blocks x 256 thr (4 waves).
// Block = 16 tokens; wave w = K-slice [w*1024, w*1024+1024), 32 steps of 32k.
// NO barriers in the K loop: each wave has a PRIVATE 3-buffer LDS dbuf for A
// (2KB/step), synced by per-wave counted s_waitcnt vmcnt(N). B is direct
// global->register from the lane-ordered blob (L2-hot, 8 x 1KB-linear/step).
// A swizzle: granule g <-> g^(row&7), pre-swizzled source + swizzled read.
// ---------------------------------------------------------------------------
__global__ __launch_bounds__(256, 4) void bulk_kernel(
    const float* __restrict__ x, const unsigned char* __restrict__ blob,
    const float* __restrict__ b,
    float* __restrict__ g_out, float* __restrict__ i_out,
    float* __restrict__ s_out,
    int* __restrict__ flag_cnt, int* __restrict__ flag_list, int flag_cap)
{
    __shared__ __align__(16) unsigned char smem[24576];  // 4 waves x 3 x 2KB

    const int tid  = threadIdx.x;
    const int l    = tid & 63;
    const int w    = tid >> 6;                // wave id == K-slice
    const int tok0 = blockIdx.x * TPB;

    unsigned char* ldsW = smem + w * 6144;    // wave-private 3-buffer region

    // ---- A staging sources (pre-swizzled; rows r0 and r0+8 share r0&7) ----
    const int g  = l & 7;
    const int r0 = l >> 3;
    const int swzf = (g ^ r0) * 4;            // float offset within 128B row-chunk
    const float* aSrc0 = x + (size_t)(tok0 + r0)     * DDIM + w * KSL + swzf;
    const float* aSrc1 = x + (size_t)(tok0 + 8 + r0) * DDIM + w * KSL + swzf;
    const unsigned char* bBase = blob + (size_t)w * 32 * 8192 + l * 16;

    // ---- compute-lane constants ----
    const int mt   = l & 15;                  // token row in fragment
    const int kgrp = l >> 4;
    const int aoff0 = mt * 128 + (((2 * kgrp)     ^ (mt & 7)) * 16);
    const int aoff1 = mt * 128 + (((2 * kgrp + 1) ^ (mt & 7)) * 16);

    f32x4 acc0 = (f32x4){0.f, 0.f, 0.f, 0.f};
    f32x4 acc1 = (f32x4){0.f, 0.f, 0.f, 0.f};
    f32x4 acc2 = (f32x4){0.f, 0.f, 0.f, 0.f};
    f32x4 acc3 = (f32x4){0.f, 0.f, 0.f, 0.f};

#define MFMA3(accv, bh, bl) do {                                              \
    accv = __builtin_amdgcn_mfma_f32_16x16x32_bf16(ah, bh, accv, 0, 0, 0);    \
    accv = __builtin_amdgcn_mfma_f32_16x16x32_bf16(ah, bl, accv, 0, 0, 0);    \
    accv = __builtin_amdgcn_mfma_f32_16x16x32_bf16(al, bh, accv, 0, 0, 0);    \
} while (0)

// Issue order per body: [B(s) 8 loads][stage(s+2) 2 gloads][wait vmcnt(NW)]
// In-order vmcnt retirement: 20 newer VMEM ops than stage(s)'s pair in steady
// state (B(s-1)8 + stage(s+1)2 + B(s)8 + stage(s+2)2) -> vmcnt(20) == stage(s)
// landed. First body: only 12 newer -> vmcnt(12).
#define BODY(sexpr, RB, SB, NW) do {                                          \
    const int _s  = (sexpr);                                                  \
    const int _sm = (_s + 2 < NSTEP) ? _s + 2 : NSTEP - 1;                    \
    const unsigned char* _pb = bBase + (size_t)_s * 8192;                     \
    short8 bh0 = *reinterpret_cast<const short8*>(_pb);                       \
    short8 bl0 = *reinterpret_cast<const short8*>(_pb + 1024);                \
    short8 bh1 = *reinterpret_cast<const short8*>(_pb + 2048);                \
    short8 bl1 = *reinterpret_cast<const short8*>(_pb + 3072);                \
    short8 bh2 = *reinterpret_cast<const short8*>(_pb + 4096);                \
    short8 bl2 = *reinterpret_cast<const short8*>(_pb + 5120);                \
    short8 bh3 = *reinterpret_cast<const short8*>(_pb + 6144);                \
    short8 bl3 = *reinterpret_cast<const short8*>(_pb + 7168);                \
    gload16(aSrc0 + _sm * 32, ldsW + (SB) * 2048 +        l * 16);            \
    gload16(aSrc1 + _sm * 32, ldsW + (SB) * 2048 + 1024 + l * 16);            \
    asm volatile("s_waitcnt vmcnt(" #NW ")" ::: "memory");                    \
    float4 A0 = *reinterpret_cast<const float4*>(ldsW + (RB) * 2048 + aoff0); \
    float4 A1 = *reinterpret_cast<const float4*>(ldsW + (RB) * 2048 + aoff1); \
    short8 ah, al;                                                            \
    CONV8(A0, A1, ah, al);                                                    \
    MFMA3(acc0, bh0, bl0);                                                    \
    MFMA3(acc1, bh1, bl1);                                                    \
    MFMA3(acc2, bh2, bl2);                                                    \
    MFMA3(acc3, bh3, bl3);                                                    \
} while (0)

    // prologue: stage steps 0,1 into bufs 0,1 (4 gloads in flight)
    gload16(aSrc0, ldsW);
    gload16(aSrc1, ldsW + 1024);
    gload16(aSrc0 + 32, ldsW + 2048);
    gload16(aSrc1 + 32, ldsW + 2048 + 1024);

    BODY(0, 0, 2, 12);
    for (int c3 = 0; c3 < 10; ++c3) {
        const int s = c3 * 3;
        BODY(s + 1, 1, 0, 20);
        BODY(s + 2, 2, 1, 20);
        BODY(s + 3, 0, 2, 20);
    }
    BODY(31, 1, 0, 20);
#undef BODY
#undef MFMA3

    __syncthreads();   // drains all waves' vm/lgkm; LDS bufs free for reuse

    // ---- K-split partials -> LDS [4][16][68] (C-frag: col=mt, row=kgrp*4+r) -
    float* red = (float*)smem;                       // 17408 B
    float* lsv = (float*)(smem + 17408);             // [16][65]
#pragma unroll
    for (int r = 0; r < 4; ++r) {
        const int t_ = kgrp * 4 + r;
        float* row = red + (w * 16 + t_) * 68;
        row[mt]      = acc0[r];
        row[16 + mt] = acc1[r];
        row[32 + mt] = acc2[r];
        row[48 + mt] = acc3[r];
    }
    __syncthreads();

    // ---- fixed-order reduce + bias + sigmoid + s_out + logits ----
    {
        const int t  = tid >> 4;                     // token 0..15
        const int e0 = (tid & 15) * 4;               // expert base
        float4 v0 = *reinterpret_cast<const float4*>(&red[(0  + t) * 68 + e0]);
        float4 v1 = *reinterpret_cast<const float4*>(&red[(16 + t) * 68 + e0]);
        float4 v2 = *reinterpret_cast<const float4*>(&red[(32 + t) * 68 + e0]);
        float4 v3 = *reinterpret_cast<const float4*>(&red[(48 + t) * 68 + e0]);
        float4 bv = *reinterpret_cast<const float4*>(&b[e0]);
        float s0 = ((v0.x + v1.x) + (v2.x + v3.x)) + bv.x;
        float s1 = ((v0.y + v1.y) + (v2.y + v3.y)) + bv.y;
        float s2 = ((v0.z + v1.z) + (v2.z + v3.z)) + bv.z;
        float s3 = ((v0.w + v1.w) + (v2.w + v3.w)) + bv.w;
        lsv[t * 65 + e0 + 0] = s0; lsv[t * 65 + e0 + 1] = s1;
        lsv[t * 65 + e0 + 2] = s2; lsv[t * 65 + e0 + 3] = s3;
        float4 sv;
        sv.x = 1.0f / (1.0f + __expf(-s0));
        sv.y = 1.0f / (1.0f + __expf(-s1));
        sv.z = 1.0f / (1.0f + __expf(-s2));
        sv.w = 1.0f / (1.0f + __expf(-s3));
        *reinterpret_cast<float4*>(&s_out[(size_t)(tok0 + t) * NEXP + e0]) = sv;
    }
    __syncthreads();

    // ---- top-10 scan, one lane per token ----
    if (tid < TPB) {
        const int t = tid;
        float val[10];
        int   idx[10];
#pragma unroll
        for (int j = 0; j < 10; ++j) { val[j] = -1e30f; idx[j] = 0; }

        for (int e = 0; e < NEXP; ++e) {
            float v = lsv[t * 65 + e];
            int  ei = e;
#pragma unroll
            for (int j = 0; j < 10; ++j) {
                if (v > val[j]) {    // strict > keeps lower index first on ties
                    float tv = val[j]; val[j] = v; v = tv;
                    int   ti = idx[j]; idx[j] = ei; ei = ti;
                }
            }
        }

        bool flag = false;
#pragma unroll
        for (int j = 0; j < 9; ++j) flag |= (val[j] - val[j + 1]) < EPS_GAP;

        float gg[TOPK], gsum = 0.0f;
#pragma unroll
        for (int j = 0; j < TOPK; ++j) {
            gg[j] = 1.0f / (1.0f + __expf(-val[j]));
            gsum += gg[j];
        }
        const float inv = 1.0f / gsum;
        const int tglob = tok0 + t;
#pragma unroll
        for (int j = 0; j < TOPK; ++j) {
            g_out[(size_t)tglob * TOPK + j] = gg[j] * inv;
            i_out[(size_t)tglob * TOPK + j] = (float)idx[j];
        }
        if (flag) {
            int p = atomicAdd(flag_cnt, 1);
            if (p < flag_cap) flag_list[p] = tglob;
        }
    }
}

// ---------------------------------------------------------------------------
// Kernel 2: f64-exact re-rank of ambiguous tokens.
// ---------------------------------------------------------------------------
__global__ __launch_bounds__(256) void refine_kernel(
    const float* __restrict__ x, const float* __restrict__ W,
    const float* __restrict__ b, float* __restrict__ g_out,
    float* __restrict__ i_out, float* __restrict__ s_out,
    const int* __restrict__ flag_cnt, const int* __restrict__ flag_list,
    int flag_cap)
{
    __shared__ float  xs2[DDIM];
    __shared__ double red[4][NEXP];
    __shared__ double sc[NEXP];

    const int tid = threadIdx.x;
    int count = *flag_cnt;
    if (count > flag_cap) count = flag_cap;

    for (int it = blockIdx.x; it < count; it += gridDim.x) {
        const int tok = flag_list[it];
        __syncthreads();
#pragma unroll
        for (int q = 0; q < 4; ++q) {
            int fi = tid + 256 * q;
            *reinterpret_cast<float4*>(&xs2[fi * 4]) =
                *reinterpret_cast<const float4*>(&x[(size_t)tok * DDIM + fi * 4]);
        }
        __syncthreads();

        const int e    = tid & 63;
        const int part = tid >> 6;
        const int dbase = part * (DDIM / 4);
        double a = 0.0;
        for (int d = 0; d < DDIM / 4; ++d) {
            a = fma((double)xs2[dbase + d],
                    (double)W[(size_t)(dbase + d) * NEXP + e], a);
        }
        red[part][e] = a;
        __syncthreads();

        if (tid < NEXP) {
            double z = ((red[0][tid] + red[1][tid]) +
                        (red[2][tid] + red[3][tid])) + (double)b[tid];
            double s = 1.0 / (1.0 + exp(-z));
            sc[tid] = s;
            s_out[(size_t)tok * NEXP + tid] = (float)s;
        }
        __syncthreads();

        if (tid == 0) {
            double val[TOPK];
            int    idx[TOPK];
#pragma unroll
            for (int j = 0; j < TOPK; ++j) { val[j] = -1e30; idx[j] = 0; }
            for (int e2 = 0; e2 < NEXP; ++e2) {
                double v = sc[e2];
                int   ei = e2;
#pragma unroll
                for (int j = 0; j < TOPK; ++j) {
                    if (v > val[j]) {
                        double tv = val[j]; val[j] = v; v = tv;
                        int    ti = idx[j]; idx[j] = ei; ei = ti;
                    }
                }
            }
            double gsum = 0.0;
#pragma unroll
            for (int j = 0; j < TOPK; ++j) gsum += val[j];
            const double inv = 1.0 / gsum;
#pragma unroll
            for (int j = 0; j < TOPK; ++j) {
                g_out[(size_t)tok * TOPK + j] = (float)(val[j] * inv);
                i_out[(size_t)tok * TOPK + j] = (float)idx[j];
            }
        }
        __syncthreads();
    }
}

// ---------------------------------------------------------------------------
extern "C" void kernel_launch(void* const* d_in, const int* in_sizes, int n_in,
                              void* d_out, int out_size, void* d_ws, size_t ws_size,
                              hipStream_t stream)
{
    (void)in_sizes; (void)n_in; (void)out_size;
    const float* x = (const float*)d_in[0];
    const float* W = (const float*)d_in[1];
    const float* b = (const float*)d_in[2];

    float* g_out = (float*)d_out;                       // [NTOK, 8]
    float* i_out = g_out + (size_t)NTOK * TOPK;         // [NTOK, 8] indices as float
    float* s_out = i_out + (size_t)NTOK * TOPK;         // [NTOK, 64]

    const size_t OFF_BLOB = 131072;
    const size_t WS_NEED  = OFF_BLOB + 128u * 8192u;    // +1 MB blob
    if (ws_size < WS_NEED) return;

    char* ws = (char*)d_ws;
    int* cnt  = (int*)ws;
    int* list = (int*)(ws + 16);
    unsigned char* blob = (unsigned char*)(ws + OFF_BLOB);
    int cap = NTOK;

    prep_w<<<128, 256, 0, stream>>>(W, blob, cnt);
    bulk_kernel<<<NTOK / TPB, 256, 0, stream>>>(x, blob, b,
                                                g_out, i_out, s_out,
                                                cnt, list, cap);
    refine_kernel<<<256, 256, 0, stream>>>(x, W, b, g_out, i_out, s_out,
                                           cnt, list, cap);
}

// Round 11
// 207.662 us; speedup vs baseline: 1.0679x; 1.0679x over previous
//
#include <hip/hip_runtime.h>
#include <cmath>

// Problem constants (B=4, S=4096, D=4096, E=64, K=8)
#define NTOK 16384
#define DDIM 4096
#define NEXP 64
#define TOPK 8
#define TPB   32                // tokens per block
#define NSTEP 64                // K steps of 64
#define EPS_GAP 2.5e-4f         // ambiguity margin; f16 hi/lo err sigma ~3e-6
#define INV2048 4.8828125e-4f

typedef __attribute__((ext_vector_type(8))) _Float16 half8;  // 8 f16 (4 VGPRs)
typedef __attribute__((ext_vector_type(4))) float f32x4;

// ---------------------------------------------------------------------------
// Kernel 0: W[4096][64] fp32 -> f16 hi/lo blob in fragment-LANE order.
// blob[m 0..127][q 0..3][hl 0..1][lane l*16B]; expert e=q*16+(l&15),
// k = m*32 + (l>>4)*8 + j. lo is scaled by 2048 (avoids f16 denormals).
// A wave's B-read per step = four wave-linear 1KB loads (L2-resident).
// ---------------------------------------------------------------------------
__global__ __launch_bounds__(256) void prep_w(const float* __restrict__ W,
                                              unsigned char* __restrict__ blob,
                                              int* __restrict__ cnts)
{
    __shared__ float tile[32][65];
    const int m = blockIdx.x;                 // K32 window [m*32, m*32+32)
    const int t = threadIdx.x;
    if (m == 0 && t < 4) cnts[t] = 0;
    {
        const int r = t >> 3, q8 = t & 7;
        float4 v0 = *reinterpret_cast<const float4*>(
            &W[(size_t)(m * 32 + r) * NEXP + q8 * 8]);
        float4 v1 = *reinterpret_cast<const float4*>(
            &W[(size_t)(m * 32 + r) * NEXP + q8 * 8 + 4]);
        tile[r][q8 * 8 + 0] = v0.x; tile[r][q8 * 8 + 1] = v0.y;
        tile[r][q8 * 8 + 2] = v0.z; tile[r][q8 * 8 + 3] = v0.w;
        tile[r][q8 * 8 + 4] = v1.x; tile[r][q8 * 8 + 5] = v1.y;
        tile[r][q8 * 8 + 6] = v1.z; tile[r][q8 * 8 + 7] = v1.w;
    }
    __syncthreads();
    {
        const int q = t >> 6, l = t & 63;
        const int e = q * 16 + (l & 15), kg = l >> 4;
        half8 hv, lv;
#pragma unroll
        for (int j = 0; j < 8; ++j) {
            float f = tile[kg * 8 + j][e];
            _Float16 h = (_Float16)f;
            hv[j] = h;
            lv[j] = (_Float16)((f - (float)h) * 2048.0f);
        }
        unsigned char* base = blob + (size_t)m * 8192 + q * 2048 + l * 16;
        *reinterpret_cast<half8*>(base)        = hv;
        *reinterpret_cast<half8*>(base + 1024) = lv;
    }
}

// ---------------------------------------------------------------------------
// Kernel 1: f16 hi/lo MFMA GEMM, conversion hoisted to staging.
// 512 blocks x 512 thr (8 waves = [tg 2 tokgrp] x [n 2 exphalf] x [kh 2 Khalf]).
// Per step c (K64): A tile 32tok x 64k f16-hi/lo staged to LDS by the
// parity kh-group (reg-staged: global fp32 -> cvt -> ds_write); each wave
// reads 1 hi + 1 lo b128, loads 4 B granules direct-to-reg (prefetched one
// step ahead), 6 MFMA (main acc + 2048-scaled cross acc). Raw s_barrier +
// lgkmcnt(0) only -- global prefetches stay in flight across barriers.
// K-halves reduced through LDS at the end (R7-verified mapping).
// ---------------------------------------------------------------------------
__global__ __launch_bounds__(512, 4) void bulk_kernel(
    const float* __restrict__ x, const unsigned char* __restrict__ blob,
    const float* __restrict__ b,
    float* __restrict__ g_out, float* __restrict__ i_out,
    float* __restrict__ s_out,
    int* __restrict__ flag_cnt, int* __restrict__ flag_list, int flag_cap)
{
    // LDS: A dbuf 2x8KB | red [2][32][68] f32 (17408B) | ls [32][65] f32
    __shared__ __align__(16) unsigned char smem[42112];

    const int tid  = threadIdx.x;
    const int l    = tid & 63;
    const int w    = tid >> 6;
    const int tg   = w & 1;
    const int n    = (w >> 1) & 1;
    const int kh   = w >> 2;                  // K-half group (also stager parity)
    const int tok0 = blockIdx.x * TPB;

    // ---- stager mapping (within the 256-thread kh-group) ----
    const int sidx = tid & 255;
    const int st   = sidx >> 3;               // token 0..31
    const int sg   = sidx & 7;                // k-oct 0..7
    const float* aSrc = x + (size_t)(tok0 + st) * DDIM + sg * 8;
    const int wOff = st * 256 + 32 * (sg ^ (st & 7));   // swizzled LDS offset

    // ---- compute-lane constants ----
    const int mt   = l & 15;
    const int kgrp = (l >> 4) & 3;
    const int tkn  = tg * 16 + mt;
    const int rdOff = tkn * 256 + 32 * (((kh << 2) + kgrp) ^ (tkn & 7));
    const unsigned char* bBase = blob + n * 4096 + l * 16;

    f32x4 accM0 = (f32x4){0.f,0.f,0.f,0.f}, accC0 = (f32x4){0.f,0.f,0.f,0.f};
    f32x4 accM1 = (f32x4){0.f,0.f,0.f,0.f}, accC1 = (f32x4){0.f,0.f,0.f,0.f};

    float4 ga0, ga1;
#define LOADG(s) do {                                                         \
    ga0 = *reinterpret_cast<const float4*>(aSrc + (size_t)(s) * 64);          \
    ga1 = *reinterpret_cast<const float4*>(aSrc + (size_t)(s) * 64 + 4);      \
} while (0)

#define CVTW(bufsel) do {                                                     \
    half8 hv, lv;                                                             \
    float av0=ga0.x, av1=ga0.y, av2=ga0.z, av3=ga0.w;                         \
    float av4=ga1.x, av5=ga1.y, av6=ga1.z, av7=ga1.w;                         \
    _Float16 h0=(_Float16)av0; hv[0]=h0; lv[0]=(_Float16)((av0-(float)h0)*2048.0f); \
    _Float16 h1=(_Float16)av1; hv[1]=h1; lv[1]=(_Float16)((av1-(float)h1)*2048.0f); \
    _Float16 h2=(_Float16)av2; hv[2]=h2; lv[2]=(_Float16)((av2-(float)h2)*2048.0f); \
    _Float16 h3=(_Float16)av3; hv[3]=h3; lv[3]=(_Float16)((av3-(float)h3)*2048.0f); \
    _Float16 h4=(_Float16)av4; hv[4]=h4; lv[4]=(_Float16)((av4-(float)h4)*2048.0f); \
    _Float16 h5=(_Float16)av5; hv[5]=h5; lv[5]=(_Float16)((av5-(float)h5)*2048.0f); \
    _Float16 h6=(_Float16)av6; hv[6]=h6; lv[6]=(_Float16)((av6-(float)h6)*2048.0f); \
    _Float16 h7=(_Float16)av7; hv[7]=h7; lv[7]=(_Float16)((av7-(float)h7)*2048.0f); \
    unsigned char* _d = smem + (bufsel) * 8192 + wOff;                        \
    *reinterpret_cast<half8*>(_d)      = hv;                                  \
    *reinterpret_cast<half8*>(_d + 16) = lv;                                  \
} while (0)

#define LOADB(mi, b0h, b0l, b1h, b1l) do {                                    \
    const unsigned char* _pb = bBase + (size_t)(mi) * 8192;                   \
    b0h = *reinterpret_cast<const half8*>(_pb);                               \
    b0l = *reinterpret_cast<const half8*>(_pb + 1024);                        \
    b1h = *reinterpret_cast<const half8*>(_pb + 2048);                        \
    b1l = *reinterpret_cast<const half8*>(_pb + 3072);                        \
} while (0)

    // ---- prologue: stage step 0 (kh0), issue step 1 (kh1), preload B(0) ----
    half8 bh0c, bl0c, bh1c, bl1c, bh0n, bl0n, bh1n, bl1n;
    if (kh == 0) { LOADG(0); CVTW(0); }
    else        { LOADG(1); }
    LOADB(kh, bh0c, bl0c, bh1c, bl1c);        // step 0: m = kh
    asm volatile("s_waitcnt lgkmcnt(0)" ::: "memory");
    __builtin_amdgcn_s_barrier();
    __builtin_amdgcn_sched_barrier(0);

    for (int c = 0; c < NSTEP; ++c) {
        // B prefetch for step c+1 (clamped dup at tail)
        const int cn = (c + 1 < NSTEP) ? c + 1 : c;
        LOADB(2 * cn + kh, bh0n, bl0n, bh1n, bl1n);
        // A global issue for step c+2 (parity group c&1)
        if (kh == (c & 1)) {
            const int s2 = (c + 2 < NSTEP) ? c + 2 : NSTEP - 1;
            LOADG(s2);
        }
        // compute step c from buf c&1
        {
            const unsigned char* ab = smem + (c & 1) * 8192 + rdOff;
            half8 ah = *reinterpret_cast<const half8*>(ab);
            half8 al = *reinterpret_cast<const half8*>(ab + 16);
            __builtin_amdgcn_s_setprio(1);
            accM0 = __builtin_amdgcn_mfma_f32_16x16x32_f16(ah, bh0c, accM0, 0, 0, 0);
            accC0 = __builtin_amdgcn_mfma_f32_16x16x32_f16(ah, bl0c, accC0, 0, 0, 0);
            accC0 = __builtin_amdgcn_mfma_f32_16x16x32_f16(al, bh0c, accC0, 0, 0, 0);
            accM1 = __builtin_amdgcn_mfma_f32_16x16x32_f16(ah, bh1c, accM1, 0, 0, 0);
            accC1 = __builtin_amdgcn_mfma_f32_16x16x32_f16(ah, bl1c, accC1, 0, 0, 0);
            accC1 = __builtin_amdgcn_mfma_f32_16x16x32_f16(al, bh1c, accC1, 0, 0, 0);
            __builtin_amdgcn_s_setprio(0);
        }
        // write step c+1 tile (parity group (c+1)&1)
        if ((kh == ((c + 1) & 1)) && (c + 1 < NSTEP)) CVTW((c + 1) & 1);
        asm volatile("s_waitcnt lgkmcnt(0)" ::: "memory");
        __builtin_amdgcn_s_barrier();
        __builtin_amdgcn_sched_barrier(0);
        bh0c = bh0n; bl0c = bl0n; bh1c = bh1n; bl1c = bl1n;
    }
#undef LOADG
#undef CVTW
#undef LOADB

    // ---- K-half partials -> LDS red[2][32][68] ----
    float* redf = (float*)(smem + 16384);
    float* lsf  = (float*)(smem + 33792);     // [32][65]
#pragma unroll
    for (int r = 0; r < 4; ++r) {
        const int t_ = tg * 16 + kgrp * 4 + r;
        redf[(kh * 32 + t_) * 68 + n * 32 + mt]      = accM0[r] + accC0[r] * INV2048;
        redf[(kh * 32 + t_) * 68 + n * 32 + 16 + mt] = accM1[r] + accC1[r] * INV2048;
    }
    __syncthreads();

    // ---- fixed-order reduce + bias + sigmoid + s_out + logits ----
    {
        const int t  = tid >> 4;              // token 0..31
        const int e0 = (tid & 15) * 4;
        float4 v0 = *reinterpret_cast<const float4*>(&redf[t * 68 + e0]);
        float4 v1 = *reinterpret_cast<const float4*>(&redf[(32 + t) * 68 + e0]);
        float4 bv = *reinterpret_cast<const float4*>(&b[e0]);
        float s0 = v0.x + v1.x + bv.x;
        float s1 = v0.y + v1.y + bv.y;
        float s2 = v0.z + v1.z + bv.z;
        float s3 = v0.w + v1.w + bv.w;
        lsf[t * 65 + e0 + 0] = s0; lsf[t * 65 + e0 + 1] = s1;
        lsf[t * 65 + e0 + 2] = s2; lsf[t * 65 + e0 + 3] = s3;
        float4 sv;
        sv.x = 1.0f / (1.0f + __expf(-s0));
        sv.y = 1.0f / (1.0f + __expf(-s1));
        sv.z = 1.0f / (1.0f + __expf(-s2));
        sv.w = 1.0f / (1.0f + __expf(-s3));
        *reinterpret_cast<float4*>(&s_out[(size_t)(tok0 + t) * NEXP + e0]) = sv;
    }
    __syncthreads();

    // ---- top-10 scan, one lane per token ----
    if (tid < TPB) {
        const int t = tid;
        float val[10];
        int   idx[10];
#pragma unroll
        for (int j = 0; j < 10; ++j) { val[j] = -1e30f; idx[j] = 0; }

        for (int e = 0; e < NEXP; ++e) {
            float v = lsf[t * 65 + e];
            int  ei = e;
#pragma unroll
            for (int j = 0; j < 10; ++j) {
                if (v > val[j]) {    // strict > keeps lower index first on ties
                    float tv = val[j]; val[j] = v; v = tv;
                    int   ti = idx[j]; idx[j] = ei; ei = ti;
                }
            }
        }

        bool flag = false;
#pragma unroll
        for (int j = 0; j < 9; ++j) flag |= (val[j] - val[j + 1]) < EPS_GAP;

        float gg[TOPK], gsum = 0.0f;
#pragma unroll
        for (int j = 0; j < TOPK; ++j) {
            gg[j] = 1.0f / (1.0f + __expf(-val[j]));
            gsum += gg[j];
        }
        const float inv = 1.0f / gsum;
        const int tglob = tok0 + t;
#pragma unroll
        for (int j = 0; j < TOPK; ++j) {
            g_out[(size_t)tglob * TOPK + j] = gg[j] * inv;
            i_out[(size_t)tglob * TOPK + j] = (float)idx[j];
        }
        if (flag) {
            int p = atomicAdd(flag_cnt, 1);
            if (p < flag_cap) flag_list[p] = tglob;
        }
    }
}

// ---------------------------------------------------------------------------
// Kernel 2: f64-exact re-rank of ambiguous tokens (unchanged, verified).
// ---------------------------------------------------------------------------
__global__ __launch_bounds__(256) void refine_kernel(
    const float* __restrict__ x, const float* __restrict__ W,
    const float* __restrict__ b, float* __restrict__ g_out,
    float* __restrict__ i_out, float* __restrict__ s_out,
    const int* __restrict__ flag_cnt, const int* __restrict__ flag_list,
    int flag_cap)
{
    __shared__ float  xs2[DDIM];
    __shared__ double red[4][NEXP];
    __shared__ double sc[NEXP];

    const int tid = threadIdx.x;
    int count = *flag_cnt;
    if (count > flag_cap) count = flag_cap;

    for (int it = blockIdx.x; it < count; it += gridDim.x) {
        const int tok = flag_list[it];
        __syncthreads();
#pragma unroll
        for (int q = 0; q < 4; ++q) {
            int fi = tid + 256 * q;
            *reinterpret_cast<float4*>(&xs2[fi * 4]) =
                *reinterpret_cast<const float4*>(&x[(size_t)tok * DDIM + fi * 4]);
        }
        __syncthreads();

        const int e    = tid & 63;
        const int part = tid >> 6;
        const int dbase = part * (DDIM / 4);
        double a = 0.0;
        for (int d = 0; d < DDIM / 4; ++d) {
            a = fma((double)xs2[dbase + d],
                    (double)W[(size_t)(dbase + d) * NEXP + e], a);
        }
        red[part][e] = a;
        __syncthreads();

        if (tid < NEXP) {
            double z = ((red[0][tid] + red[1][tid]) +
                        (red[2][tid] + red[3][tid])) + (double)b[tid];
            double s = 1.0 / (1.0 + exp(-z));
            sc[tid] = s;
            s_out[(size_t)tok * NEXP + tid] = (float)s;
        }
        __syncthreads();

        if (tid == 0) {
            double val[TOPK];
            int    idx[TOPK];
#pragma unroll
            for (int j = 0; j < TOPK; ++j) { val[j] = -1e30; idx[j] = 0; }
            for (int e2 = 0; e2 < NEXP; ++e2) {
                double v = sc[e2];
                int   ei = e2;
#pragma unroll
                for (int j = 0; j < TOPK; ++j) {
                    if (v > val[j]) {
                        double tv = val[j]; val[j] = v; v = tv;
                        int    ti = idx[j]; idx[j] = ei; ei = ti;
                    }
                }
            }
            double gsum = 0.0;
#pragma unroll
            for (int j = 0; j < TOPK; ++j) gsum += val[j];
            const double inv = 1.0 / gsum;
#pragma unroll
            for (int j = 0; j < TOPK; ++j) {
                g_out[(size_t)tok * TOPK + j] = (float)(val[j] * inv);
                i_out[(size_t)tok * TOPK + j] = (float)idx[j];
            }
        }
        __syncthreads();
    }
}

// ---------------------------------------------------------------------------
extern "C" void kernel_launch(void* const* d_in, const int* in_sizes, int n_in,
                              void* d_out, int out_size, void* d_ws, size_t ws_size,
                              hipStream_t stream)
{
    (void)in_sizes; (void)n_in; (void)out_size;
    const float* x = (const float*)d_in[0];
    const float* W = (const float*)d_in[1];
    const float* b = (const float*)d_in[2];

    float* g_out = (float*)d_out;                       // [NTOK, 8]
    float* i_out = g_out + (size_t)NTOK * TOPK;         // [NTOK, 8] indices as float
    float* s_out = i_out + (size_t)NTOK * TOPK;         // [NTOK, 64]

    const size_t OFF_BLOB = 131072;
    const size_t WS_NEED  = OFF_BLOB + 128u * 8192u;    // +1 MB blob
    if (ws_size < WS_NEED) return;

    char* ws = (char*)d_ws;
    int* cnt  = (int*)ws;
    int* list = (int*)(ws + 16);
    unsigned char* blob = (unsigned char*)(ws + OFF_BLOB);
    int cap = NTOK;

    prep_w<<<128, 256, 0, stream>>>(W, blob, cnt);
    bulk_kernel<<<NTOK / TPB, 512, 0, stream>>>(x, blob, b,
                                                g_out, i_out, s_out,
                                                cnt, list, cap);
    refine_kernel<<<256, 256, 0, stream>>>(x, W, b, g_out, i_out, s_out,
                                           cnt, list, cap);
}